// Round 1
// baseline (11493.539 us; speedup 1.0000x reference)
//
#include <hip/hip_runtime.h>

#define N_NODES 50000
#define N_EDGES 800000
#define N_GRAPHS 2048
#define IN_DIM 128
#define HID 256
#define N_LAYERS 4
#define BN_EPS 1e-5f

// ---------------- degree / norm ----------------
__global__ void k_deg(const int* __restrict__ dst, int* __restrict__ degi, int E) {
    int e = blockIdx.x * blockDim.x + threadIdx.x;
    if (e < E) atomicAdd(&degi[dst[e]], 1);
}

__global__ void k_nodenorm(const int* __restrict__ degi, float* __restrict__ dinv,
                           float* __restrict__ selfn, int N) {
    int n = blockIdx.x * blockDim.x + threadIdx.x;
    if (n < N) {
        float d = 1.0f + (float)degi[n];
        dinv[n] = 1.0f / sqrtf(d);
        selfn[n] = 1.0f / d;
    }
}

__global__ void k_enorm(const int* __restrict__ src, const int* __restrict__ dst,
                        const float* __restrict__ dinv, float* __restrict__ enorm, int E) {
    int e = blockIdx.x * blockDim.x + threadIdx.x;
    if (e < E) enorm[e] = dinv[src[e]] * dinv[dst[e]];
}

// ---------------- SGEMM: H = A[NxK] @ W[Kx256]; AGG = H*selfn[row] + bias[col] ----------------
// 64x64 tile, BK=16, 256 threads, 4x4 micro-tile per thread.
__global__ __launch_bounds__(256) void k_gemm(const float* __restrict__ A,
                                              const float* __restrict__ W,
                                              const float* __restrict__ bias,
                                              const float* __restrict__ selfn,
                                              float* __restrict__ H,
                                              float* __restrict__ AGG,
                                              int N, int K) {
    __shared__ float As[16][65];
    __shared__ float Ws[16][65];
    int tid = threadIdx.x;
    int tx = tid & 15;        // col group (0..15)
    int ty = tid >> 4;        // row group (0..15)
    int row0 = blockIdx.x * 64;
    int col0 = blockIdx.y * 64;

    int lr = tid >> 2;          // 0..63 : A-tile row
    int lk = (tid & 3) * 4;     // 0,4,8,12 : A-tile k offset
    int wk = tid >> 4;          // 0..15 : W-tile k row
    int wc = (tid & 15) * 4;    // 0..60 : W-tile col offset

    float acc[4][4] = {};

    for (int k0 = 0; k0 < K; k0 += 16) {
        float4 av = make_float4(0.f, 0.f, 0.f, 0.f);
        int ar = row0 + lr;
        if (ar < N) av = *(const float4*)(A + (size_t)ar * K + k0 + lk);
        As[lk + 0][lr] = av.x;
        As[lk + 1][lr] = av.y;
        As[lk + 2][lr] = av.z;
        As[lk + 3][lr] = av.w;

        float4 wv = *(const float4*)(W + (size_t)(k0 + wk) * HID + col0 + wc);
        Ws[wk][wc + 0] = wv.x;
        Ws[wk][wc + 1] = wv.y;
        Ws[wk][wc + 2] = wv.z;
        Ws[wk][wc + 3] = wv.w;

        __syncthreads();
        #pragma unroll
        for (int kk = 0; kk < 16; ++kk) {
            float a[4], b[4];
            #pragma unroll
            for (int i = 0; i < 4; ++i) a[i] = As[kk][ty * 4 + i];
            #pragma unroll
            for (int j = 0; j < 4; ++j) b[j] = Ws[kk][tx * 4 + j];
            #pragma unroll
            for (int i = 0; i < 4; ++i)
                #pragma unroll
                for (int j = 0; j < 4; ++j)
                    acc[i][j] += a[i] * b[j];
        }
        __syncthreads();
    }

    int c = col0 + tx * 4;
    float4 bv = *(const float4*)(bias + c);
    #pragma unroll
    for (int i = 0; i < 4; ++i) {
        int r = row0 + ty * 4 + i;
        if (r >= N) continue;
        float sn = selfn[r];
        float4 h = make_float4(acc[i][0], acc[i][1], acc[i][2], acc[i][3]);
        *(float4*)(H + (size_t)r * HID + c) = h;
        float4 ag;
        ag.x = h.x * sn + bv.x;
        ag.y = h.y * sn + bv.y;
        ag.z = h.z * sn + bv.z;
        ag.w = h.w * sn + bv.w;
        *(float4*)(AGG + (size_t)r * HID + c) = ag;
    }
}

// ---------------- edge scatter: AGG[dst] += H[src] * enorm ----------------
// one wave (64 lanes) per edge; lane covers 4 channels (float4 gather, 4 atomics)
__global__ __launch_bounds__(256) void k_scatter(const float* __restrict__ H,
                                                 const int* __restrict__ src,
                                                 const int* __restrict__ dst,
                                                 const float* __restrict__ enorm,
                                                 float* __restrict__ AGG, int E) {
    int e = blockIdx.x * 4 + (threadIdx.x >> 6);
    int lane = threadIdx.x & 63;
    if (e >= E) return;
    int s = src[e];
    int d = dst[e];
    float w = enorm[e];
    float4 v = *(const float4*)(H + (size_t)s * HID + lane * 4);
    float* ag = AGG + (size_t)d * HID + lane * 4;
    atomicAdd(ag + 0, v.x * w);
    atomicAdd(ag + 1, v.y * w);
    atomicAdd(ag + 2, v.z * w);
    atomicAdd(ag + 3, v.w * w);
}

// ---------------- BN prep + BN/ReLU ----------------
__global__ void k_bnprep(const float* __restrict__ gamma, const float* __restrict__ beta,
                         const float* __restrict__ mean, const float* __restrict__ var,
                         float* __restrict__ scale, float* __restrict__ shift) {
    int c = threadIdx.x;
    if (c < HID) {
        float s = gamma[c] / sqrtf(var[c] + BN_EPS);
        scale[c] = s;
        shift[c] = beta[c] - mean[c] * s;
    }
}

__global__ __launch_bounds__(256) void k_bnrelu(const float* __restrict__ AGG,
                                                const float* __restrict__ scale,
                                                const float* __restrict__ shift,
                                                float* __restrict__ X, int total4) {
    int i = blockIdx.x * blockDim.x + threadIdx.x;
    if (i >= total4) return;
    int c = (i * 4) & (HID - 1);
    float4 a = ((const float4*)AGG)[i];
    float4 o;
    o.x = fmaxf(a.x * scale[c + 0] + shift[c + 0], 0.f);
    o.y = fmaxf(a.y * scale[c + 1] + shift[c + 1], 0.f);
    o.z = fmaxf(a.z * scale[c + 2] + shift[c + 2], 0.f);
    o.w = fmaxf(a.w * scale[c + 3] + shift[c + 3], 0.f);
    ((float4*)X)[i] = o;
}

// ---------------- mean pool (atomic) ----------------
__global__ __launch_bounds__(256) void k_pool(const float* __restrict__ X,
                                              const int* __restrict__ batch,
                                              float* __restrict__ pooled,
                                              int* __restrict__ cnt, int N) {
    int n = blockIdx.x * 4 + (threadIdx.x >> 6);
    int lane = threadIdx.x & 63;
    if (n >= N) return;
    int g = batch[n];
    float4 v = *(const float4*)(X + (size_t)n * HID + lane * 4);
    float* p = pooled + (size_t)g * HID + lane * 4;
    atomicAdd(p + 0, v.x);
    atomicAdd(p + 1, v.y);
    atomicAdd(p + 2, v.z);
    atomicAdd(p + 3, v.w);
    if (lane == 0) atomicAdd(&cnt[g], 1);
}

// ---------------- MLP head: out[g] = relu(mean @ W1 + b1) @ W2 + b2 ----------------
__global__ __launch_bounds__(128) void k_mlp(const float* __restrict__ pooled,
                                             const int* __restrict__ cnt,
                                             const float* __restrict__ W1,
                                             const float* __restrict__ b1,
                                             const float* __restrict__ W2,
                                             const float* __restrict__ b2,
                                             float* __restrict__ out) {
    __shared__ float prow[HID];
    __shared__ float hred[2];
    int g = blockIdx.x;
    int j = threadIdx.x; // 0..127
    prow[j] = pooled[(size_t)g * HID + j];
    prow[j + 128] = pooled[(size_t)g * HID + 128 + j];
    __syncthreads();
    float acc = 0.f;
    #pragma unroll 8
    for (int k = 0; k < HID; ++k) acc += prow[k] * W1[k * 128 + j];
    float inv = 1.0f / fmaxf((float)cnt[g], 1.0f);
    float h = fmaxf(acc * inv + b1[j], 0.f);
    float p = h * W2[j];
    #pragma unroll
    for (int off = 32; off > 0; off >>= 1) p += __shfl_down(p, off, 64);
    if ((j & 63) == 0) hred[j >> 6] = p;
    __syncthreads();
    if (j == 0) out[g] = hred[0] + hred[1] + b2[0];
}

extern "C" void kernel_launch(void* const* d_in, const int* in_sizes, int n_in,
                              void* d_out, int out_size, void* d_ws, size_t ws_size,
                              hipStream_t stream) {
    const float* x      = (const float*)d_in[0];
    const int*   ei     = (const int*)d_in[1];
    const int*   batch  = (const int*)d_in[2];
    const float* convW0 = (const float*)d_in[3];
    const float* convWs = (const float*)d_in[4];
    const float* convB  = (const float*)d_in[5];
    const float* gamma  = (const float*)d_in[6];
    const float* beta   = (const float*)d_in[7];
    const float* mean   = (const float*)d_in[8];
    const float* var    = (const float*)d_in[9];
    const float* lin1W  = (const float*)d_in[10];
    const float* lin1b  = (const float*)d_in[11];
    const float* lin2W  = (const float*)d_in[12];
    const float* lin2b  = (const float*)d_in[13];
    float* out = (float*)d_out;

    const int* src = ei;
    const int* dst = ei + N_EDGES;

    // workspace layout (fp32 elements)
    float* ws = (float*)d_ws;
    float* xbuf   = ws;                          // N*HID
    float* hbuf   = xbuf + (size_t)N_NODES * HID; // N*HID
    float* aggbuf = hbuf + (size_t)N_NODES * HID; // N*HID
    float* dinv   = aggbuf + (size_t)N_NODES * HID; // N
    float* selfn  = dinv + N_NODES;              // N
    float* enorm  = selfn + N_NODES;             // E
    float* pooled = enorm + N_EDGES;             // G*HID
    int*   cnt    = (int*)(pooled + (size_t)N_GRAPHS * HID); // G
    int*   degi   = cnt + N_GRAPHS;              // N
    float* bnscale = (float*)(degi + N_NODES);   // HID
    float* bnshift = bnscale + HID;              // HID

    hipMemsetAsync(degi, 0, (size_t)N_NODES * 4, stream);
    hipMemsetAsync(pooled, 0, ((size_t)N_GRAPHS * HID + N_GRAPHS) * 4, stream);

    k_deg<<<(N_EDGES + 255) / 256, 256, 0, stream>>>(dst, degi, N_EDGES);
    k_nodenorm<<<(N_NODES + 255) / 256, 256, 0, stream>>>(degi, dinv, selfn, N_NODES);
    k_enorm<<<(N_EDGES + 255) / 256, 256, 0, stream>>>(src, dst, dinv, enorm, N_EDGES);

    for (int l = 0; l < N_LAYERS; ++l) {
        const float* A = (l == 0) ? x : xbuf;
        int K = (l == 0) ? IN_DIM : HID;
        const float* W = (l == 0) ? convW0 : (convWs + (size_t)(l - 1) * HID * HID);
        const float* b = convB + (size_t)l * HID;

        dim3 gg((N_NODES + 63) / 64, HID / 64);
        k_gemm<<<gg, 256, 0, stream>>>(A, W, b, selfn, hbuf, aggbuf, N_NODES, K);
        k_scatter<<<(N_EDGES + 3) / 4, 256, 0, stream>>>(hbuf, src, dst, enorm, aggbuf, N_EDGES);
        k_bnprep<<<1, 256, 0, stream>>>(gamma + (size_t)l * HID, beta + (size_t)l * HID,
                                        mean + (size_t)l * HID, var + (size_t)l * HID,
                                        bnscale, bnshift);
        int total4 = N_NODES * HID / 4;
        k_bnrelu<<<(total4 + 255) / 256, 256, 0, stream>>>(aggbuf, bnscale, bnshift, xbuf, total4);
    }

    k_pool<<<(N_NODES + 3) / 4, 256, 0, stream>>>(xbuf, batch, pooled, cnt, N_NODES);
    k_mlp<<<N_GRAPHS, 128, 0, stream>>>(pooled, cnt, lin1W, lin1b, lin2W, lin2b, out);
}

// Round 2
// 1266.293 us; speedup vs baseline: 9.0765x; 9.0765x over previous
//
#include <hip/hip_runtime.h>

#define N_NODES 50000
#define N_EDGES 800000
#define N_GRAPHS 2048
#define IN_DIM 128
#define HID 256
#define N_LAYERS 4
#define BN_EPS 1e-5f

// ---------------- degree count ----------------
__global__ void k_deg(const int* __restrict__ dst, int* __restrict__ degi, int E) {
    int e = blockIdx.x * blockDim.x + threadIdx.x;
    if (e < E) atomicAdd(&degi[dst[e]], 1);
}

__global__ void k_nodenorm(const int* __restrict__ degi, float* __restrict__ dinv,
                           float* __restrict__ selfn, int N) {
    int n = blockIdx.x * blockDim.x + threadIdx.x;
    if (n < N) {
        float d = 1.0f + (float)degi[n];
        dinv[n] = 1.0f / sqrtf(d);
        selfn[n] = 1.0f / d;
    }
}

// ---------------- exclusive prefix scan of degi -> rowstart/cursor (single block) ----------------
__global__ __launch_bounds__(1024) void k_scan(const int* __restrict__ degi,
                                               int* __restrict__ rowstart,
                                               int* __restrict__ cursor, int N) {
    __shared__ int part[1024];
    int t = threadIdx.x;
    int chunk = (N + 1023) / 1024;
    int b = t * chunk;
    int e = min(b + chunk, N);
    int s = 0;
    for (int i = b; i < e; ++i) s += degi[i];
    part[t] = s;
    __syncthreads();
    // inclusive Hillis-Steele scan
    for (int off = 1; off < 1024; off <<= 1) {
        int v = (t >= off) ? part[t - off] : 0;
        __syncthreads();
        part[t] += v;
        __syncthreads();
    }
    int run = (t == 0) ? 0 : part[t - 1]; // exclusive base for this chunk
    for (int i = b; i < e; ++i) {
        rowstart[i] = run;
        cursor[i] = run;
        run += degi[i];
    }
    if (t == 1023) rowstart[N] = run;
}

// ---------------- CSR fill: bucket edges by dst ----------------
__global__ void k_fill(const int* __restrict__ src, const int* __restrict__ dst,
                       const float* __restrict__ dinv, int* __restrict__ cursor,
                       int* __restrict__ esrc, float* __restrict__ ew, int E) {
    int e = blockIdx.x * blockDim.x + threadIdx.x;
    if (e >= E) return;
    int s = src[e], d = dst[e];
    int pos = atomicAdd(&cursor[d], 1);
    esrc[pos] = s;
    ew[pos] = dinv[s] * dinv[d];
}

// ---------------- SGEMM: H = A[NxK] @ W[Kx256] ----------------
// 64x64 tile, BK=16, 256 threads, 4x4 micro-tile per thread.
__global__ __launch_bounds__(256) void k_gemm(const float* __restrict__ A,
                                              const float* __restrict__ W,
                                              float* __restrict__ H,
                                              int N, int K) {
    __shared__ float As[16][65];
    __shared__ float Ws[16][65];
    int tid = threadIdx.x;
    int tx = tid & 15;
    int ty = tid >> 4;
    int row0 = blockIdx.x * 64;
    int col0 = blockIdx.y * 64;

    int lr = tid >> 2;
    int lk = (tid & 3) * 4;
    int wk = tid >> 4;
    int wc = (tid & 15) * 4;

    float acc[4][4] = {};

    for (int k0 = 0; k0 < K; k0 += 16) {
        float4 av = make_float4(0.f, 0.f, 0.f, 0.f);
        int ar = row0 + lr;
        if (ar < N) av = *(const float4*)(A + (size_t)ar * K + k0 + lk);
        As[lk + 0][lr] = av.x;
        As[lk + 1][lr] = av.y;
        As[lk + 2][lr] = av.z;
        As[lk + 3][lr] = av.w;

        float4 wv = *(const float4*)(W + (size_t)(k0 + wk) * HID + col0 + wc);
        Ws[wk][wc + 0] = wv.x;
        Ws[wk][wc + 1] = wv.y;
        Ws[wk][wc + 2] = wv.z;
        Ws[wk][wc + 3] = wv.w;

        __syncthreads();
        #pragma unroll
        for (int kk = 0; kk < 16; ++kk) {
            float a[4], b[4];
            #pragma unroll
            for (int i = 0; i < 4; ++i) a[i] = As[kk][ty * 4 + i];
            #pragma unroll
            for (int j = 0; j < 4; ++j) b[j] = Ws[kk][tx * 4 + j];
            #pragma unroll
            for (int i = 0; i < 4; ++i)
                #pragma unroll
                for (int j = 0; j < 4; ++j)
                    acc[i][j] += a[i] * b[j];
        }
        __syncthreads();
    }

    int c = col0 + tx * 4;
    #pragma unroll
    for (int i = 0; i < 4; ++i) {
        int r = row0 + ty * 4 + i;
        if (r >= N) continue;
        float4 h = make_float4(acc[i][0], acc[i][1], acc[i][2], acc[i][3]);
        *(float4*)(H + (size_t)r * HID + c) = h;
    }
}

// ---------------- BN prep: fold conv bias into BN affine ----------------
// out = relu( (agg_total) * scale + shift ), where agg_total excludes bias:
// scale = gamma*rsqrt(var+eps); shift = beta + (bias - mean)*scale
__global__ void k_bnprep(const float* __restrict__ gamma, const float* __restrict__ beta,
                         const float* __restrict__ mean, const float* __restrict__ var,
                         const float* __restrict__ bias,
                         float* __restrict__ scale, float* __restrict__ shift) {
    int l = blockIdx.x;
    int c = threadIdx.x;
    if (c < HID) {
        float s = gamma[l * HID + c] * rsqrtf(var[l * HID + c] + BN_EPS);
        scale[l * HID + c] = s;
        shift[l * HID + c] = beta[l * HID + c] + (bias[l * HID + c] - mean[l * HID + c]) * s;
    }
}

// ---------------- fused gather-aggregate + self-loop + BN + ReLU ----------------
// one wave per node; lane holds channels [lane*4, lane*4+4)
__global__ __launch_bounds__(256) void k_gather(const float* __restrict__ H,
                                                const int* __restrict__ rowstart,
                                                const int* __restrict__ esrc,
                                                const float* __restrict__ ew,
                                                const float* __restrict__ selfn,
                                                const float* __restrict__ bnscale,
                                                const float* __restrict__ bnshift,
                                                float* __restrict__ X, int N) {
    int node = blockIdx.x * 4 + (threadIdx.x >> 6);
    if (node >= N) return;
    int lane = threadIdx.x & 63;
    int c = lane * 4;
    int beg = rowstart[node];
    int end = rowstart[node + 1];

    float4 h = *(const float4*)(H + (size_t)node * HID + c);
    float sn = selfn[node];
    float4 acc;
    acc.x = h.x * sn;
    acc.y = h.y * sn;
    acc.z = h.z * sn;
    acc.w = h.w * sn;

    int j = beg;
    for (; j + 1 < end; j += 2) {
        int s0 = esrc[j];
        int s1 = esrc[j + 1];
        float w0 = ew[j];
        float w1 = ew[j + 1];
        float4 v0 = *(const float4*)(H + (size_t)s0 * HID + c);
        float4 v1 = *(const float4*)(H + (size_t)s1 * HID + c);
        acc.x = fmaf(v0.x, w0, acc.x); acc.x = fmaf(v1.x, w1, acc.x);
        acc.y = fmaf(v0.y, w0, acc.y); acc.y = fmaf(v1.y, w1, acc.y);
        acc.z = fmaf(v0.z, w0, acc.z); acc.z = fmaf(v1.z, w1, acc.z);
        acc.w = fmaf(v0.w, w0, acc.w); acc.w = fmaf(v1.w, w1, acc.w);
    }
    if (j < end) {
        int s0 = esrc[j];
        float w0 = ew[j];
        float4 v0 = *(const float4*)(H + (size_t)s0 * HID + c);
        acc.x = fmaf(v0.x, w0, acc.x);
        acc.y = fmaf(v0.y, w0, acc.y);
        acc.z = fmaf(v0.z, w0, acc.z);
        acc.w = fmaf(v0.w, w0, acc.w);
    }

    float4 sc = *(const float4*)(bnscale + c);
    float4 sh = *(const float4*)(bnshift + c);
    float4 o;
    o.x = fmaxf(fmaf(acc.x, sc.x, sh.x), 0.f);
    o.y = fmaxf(fmaf(acc.y, sc.y, sh.y), 0.f);
    o.z = fmaxf(fmaf(acc.z, sc.z, sh.z), 0.f);
    o.w = fmaxf(fmaf(acc.w, sc.w, sh.w), 0.f);
    *(float4*)(X + (size_t)node * HID + c) = o;
}

// ---------------- segmented mean pool (batch is sorted) ----------------
// block = 256 threads (one per channel), handles SPAN consecutive nodes;
// flush to pooled[g] with atomics only when graph id changes.
#define POOL_SPAN 25
__global__ __launch_bounds__(256) void k_pool(const float* __restrict__ X,
                                              const int* __restrict__ batch,
                                              float* __restrict__ pooled,
                                              int* __restrict__ cnt, int N) {
    int n0 = blockIdx.x * POOL_SPAN;
    int c = threadIdx.x;
    int nend = min(n0 + POOL_SPAN, N);
    float acc = 0.f;
    int curg = batch[n0];
    int segcnt = 0;
    for (int n = n0; n < nend; ++n) {
        int g = batch[n];
        if (g != curg) {
            atomicAdd(&pooled[(size_t)curg * HID + c], acc);
            if (c == 0) atomicAdd(&cnt[curg], segcnt);
            acc = 0.f;
            segcnt = 0;
            curg = g;
        }
        acc += X[(size_t)n * HID + c];
        ++segcnt;
    }
    atomicAdd(&pooled[(size_t)curg * HID + c], acc);
    if (c == 0) atomicAdd(&cnt[curg], segcnt);
}

// ---------------- MLP head ----------------
__global__ __launch_bounds__(128) void k_mlp(const float* __restrict__ pooled,
                                             const int* __restrict__ cnt,
                                             const float* __restrict__ W1,
                                             const float* __restrict__ b1,
                                             const float* __restrict__ W2,
                                             const float* __restrict__ b2,
                                             float* __restrict__ out) {
    __shared__ float prow[HID];
    __shared__ float hred[2];
    int g = blockIdx.x;
    int j = threadIdx.x; // 0..127
    prow[j] = pooled[(size_t)g * HID + j];
    prow[j + 128] = pooled[(size_t)g * HID + 128 + j];
    __syncthreads();
    float acc = 0.f;
    #pragma unroll 8
    for (int k = 0; k < HID; ++k) acc += prow[k] * W1[k * 128 + j];
    float inv = 1.0f / fmaxf((float)cnt[g], 1.0f);
    float h = fmaxf(acc * inv + b1[j], 0.f);
    float p = h * W2[j];
    #pragma unroll
    for (int off = 32; off > 0; off >>= 1) p += __shfl_down(p, off, 64);
    if ((j & 63) == 0) hred[j >> 6] = p;
    __syncthreads();
    if (j == 0) out[g] = hred[0] + hred[1] + b2[0];
}

extern "C" void kernel_launch(void* const* d_in, const int* in_sizes, int n_in,
                              void* d_out, int out_size, void* d_ws, size_t ws_size,
                              hipStream_t stream) {
    const float* x      = (const float*)d_in[0];
    const int*   ei     = (const int*)d_in[1];
    const int*   batch  = (const int*)d_in[2];
    const float* convW0 = (const float*)d_in[3];
    const float* convWs = (const float*)d_in[4];
    const float* convB  = (const float*)d_in[5];
    const float* gamma  = (const float*)d_in[6];
    const float* beta   = (const float*)d_in[7];
    const float* mean   = (const float*)d_in[8];
    const float* var    = (const float*)d_in[9];
    const float* lin1W  = (const float*)d_in[10];
    const float* lin1b  = (const float*)d_in[11];
    const float* lin2W  = (const float*)d_in[12];
    const float* lin2b  = (const float*)d_in[13];
    float* out = (float*)d_out;

    const int* src = ei;
    const int* dst = ei + N_EDGES;

    // workspace layout (fp32 elements)
    float* ws = (float*)d_ws;
    float* xbuf    = ws;                                  // N*HID
    float* hbuf    = xbuf + (size_t)N_NODES * HID;        // N*HID
    float* dinv    = hbuf + (size_t)N_NODES * HID;        // N
    float* selfn   = dinv + N_NODES;                      // N
    float* ew      = selfn + N_NODES;                     // E
    float* pooled  = ew + N_EDGES;                        // G*HID
    float* bnscale = pooled + (size_t)N_GRAPHS * HID;     // 4*HID
    float* bnshift = bnscale + N_LAYERS * HID;            // 4*HID
    int*   cnt     = (int*)(bnshift + N_LAYERS * HID);    // G
    int*   degi    = cnt + N_GRAPHS;                      // N
    int*   rowstart= degi + N_NODES;                      // N+1
    int*   cursor  = rowstart + (N_NODES + 1);            // N
    int*   esrc    = cursor + N_NODES;                    // E

    hipMemsetAsync(degi, 0, (size_t)N_NODES * 4, stream);
    hipMemsetAsync(pooled, 0, (size_t)N_GRAPHS * HID * 4, stream);
    hipMemsetAsync(cnt, 0, (size_t)N_GRAPHS * 4, stream);

    // CSR build
    k_deg<<<(N_EDGES + 255) / 256, 256, 0, stream>>>(dst, degi, N_EDGES);
    k_nodenorm<<<(N_NODES + 255) / 256, 256, 0, stream>>>(degi, dinv, selfn, N_NODES);
    k_scan<<<1, 1024, 0, stream>>>(degi, rowstart, cursor, N_NODES);
    k_fill<<<(N_EDGES + 255) / 256, 256, 0, stream>>>(src, dst, dinv, cursor, esrc, ew, N_EDGES);

    // BN affine prep for all layers (bias folded in)
    k_bnprep<<<N_LAYERS, 256, 0, stream>>>(gamma, beta, mean, var, convB, bnscale, bnshift);

    for (int l = 0; l < N_LAYERS; ++l) {
        const float* A = (l == 0) ? x : xbuf;
        int K = (l == 0) ? IN_DIM : HID;
        const float* W = (l == 0) ? convW0 : (convWs + (size_t)(l - 1) * HID * HID);

        dim3 gg((N_NODES + 63) / 64, HID / 64);
        k_gemm<<<gg, 256, 0, stream>>>(A, W, hbuf, N_NODES, K);
        k_gather<<<(N_NODES + 3) / 4, 256, 0, stream>>>(hbuf, rowstart, esrc, ew, selfn,
                                                        bnscale + l * HID, bnshift + l * HID,
                                                        xbuf, N_NODES);
    }

    k_pool<<<(N_NODES + POOL_SPAN - 1) / POOL_SPAN, 256, 0, stream>>>(xbuf, batch, pooled, cnt, N_NODES);
    k_mlp<<<N_GRAPHS, 128, 0, stream>>>(pooled, cnt, lin1W, lin1b, lin2W, lin2b, out);
}

// Round 3
// 952.851 us; speedup vs baseline: 12.0623x; 1.3290x over previous
//
#include <hip/hip_runtime.h>

#define N_NODES 50000
#define N_EDGES 800000
#define N_GRAPHS 2048
#define IN_DIM 128
#define HID 256
#define N_LAYERS 4
#define BN_EPS 1e-5f

typedef unsigned short ushort_t;
typedef __bf16 bf16x8 __attribute__((ext_vector_type(8)));
typedef float f32x4 __attribute__((ext_vector_type(4)));

// ---- fp32 -> bf16 (round-to-nearest-even) helpers ----
__device__ __forceinline__ ushort_t f2bf_rn(float x) {
    unsigned int u = __float_as_uint(x);
    u += 0x7FFFu + ((u >> 16) & 1u);
    return (ushort_t)(u >> 16);
}
__device__ __forceinline__ float bf2f(ushort_t h) {
    return __uint_as_float(((unsigned int)h) << 16);
}

// ---- async global->LDS, 16B per lane; dest = lds base + lane*16 ----
__device__ __forceinline__ void gl_lds16(const ushort_t* g, ushort_t* l) {
    __builtin_amdgcn_global_load_lds(
        (const __attribute__((address_space(1))) void*)g,
        (__attribute__((address_space(3))) void*)l, 16, 0, 0);
}

// ---------------- degree count ----------------
__global__ void k_deg(const int* __restrict__ dst, int* __restrict__ degi, int E) {
    int e = blockIdx.x * blockDim.x + threadIdx.x;
    if (e < E) atomicAdd(&degi[dst[e]], 1);
}

__global__ void k_nodenorm(const int* __restrict__ degi, float* __restrict__ dinv,
                           float* __restrict__ selfn, int N) {
    int n = blockIdx.x * blockDim.x + threadIdx.x;
    if (n < N) {
        float d = 1.0f + (float)degi[n];
        dinv[n] = 1.0f / sqrtf(d);
        selfn[n] = 1.0f / d;
    }
}

// ---------------- exclusive prefix scan (single block) ----------------
__global__ __launch_bounds__(1024) void k_scan(const int* __restrict__ degi,
                                               int* __restrict__ rowstart,
                                               int* __restrict__ cursor, int N) {
    __shared__ int part[1024];
    int t = threadIdx.x;
    int chunk = (N + 1023) / 1024;
    int b = t * chunk;
    int e = min(b + chunk, N);
    int s = 0;
    for (int i = b; i < e; ++i) s += degi[i];
    part[t] = s;
    __syncthreads();
    for (int off = 1; off < 1024; off <<= 1) {
        int v = (t >= off) ? part[t - off] : 0;
        __syncthreads();
        part[t] += v;
        __syncthreads();
    }
    int run = (t == 0) ? 0 : part[t - 1];
    for (int i = b; i < e; ++i) {
        rowstart[i] = run;
        cursor[i] = run;
        run += degi[i];
    }
    if (t == 1023) rowstart[N] = run;
}

// ---------------- CSR fill ----------------
__global__ void k_fill(const int* __restrict__ src, const int* __restrict__ dst,
                       const float* __restrict__ dinv, int* __restrict__ cursor,
                       int* __restrict__ esrc, float* __restrict__ ew, int E) {
    int e = blockIdx.x * blockDim.x + threadIdx.x;
    if (e >= E) return;
    int s = src[e], d = dst[e];
    int pos = atomicAdd(&cursor[d], 1);
    esrc[pos] = s;
    ew[pos] = dinv[s] * dinv[d];
}

// ---------------- split x -> bf16 hi/lo ----------------
__global__ __launch_bounds__(256) void k_splitx(const float* __restrict__ x,
                                                ushort_t* __restrict__ Ah,
                                                ushort_t* __restrict__ Al, int total4) {
    int i = blockIdx.x * blockDim.x + threadIdx.x;
    if (i >= total4) return;
    float4 v = ((const float4*)x)[i];
    ushort4 h, l;
    h.x = f2bf_rn(v.x); l.x = f2bf_rn(v.x - bf2f(h.x));
    h.y = f2bf_rn(v.y); l.y = f2bf_rn(v.y - bf2f(h.y));
    h.z = f2bf_rn(v.z); l.z = f2bf_rn(v.z - bf2f(h.z));
    h.w = f2bf_rn(v.w); l.w = f2bf_rn(v.w - bf2f(h.w));
    ((ushort4*)Ah)[i] = h;
    ((ushort4*)Al)[i] = l;
}

// ---------------- split + transpose weights -> [layer][n][k] bf16 hi/lo ----------------
// layout: layer0 at 0 (256n x 128k), layer l>=1 at 32768 + (l-1)*65536 (256n x 256k)
__global__ void k_splitw(const float* __restrict__ W0, const float* __restrict__ Ws,
                         ushort_t* __restrict__ Wh, ushort_t* __restrict__ Wl) {
    int i = blockIdx.x * blockDim.x + threadIdx.x;
    const int total = 128 * 256 + 3 * 256 * 256;
    if (i >= total) return;
    float v;
    if (i < 32768) {
        int n = i >> 7, k = i & 127;
        v = W0[k * 256 + n];
    } else {
        int t = i - 32768;
        int l = t >> 16;
        int r = t & 65535;
        int n = r >> 8, k = r & 255;
        v = Ws[l * 65536 + k * 256 + n];
    }
    ushort_t h = f2bf_rn(v);
    Wh[i] = h;
    Wl[i] = f2bf_rn(v - bf2f(h));
}

// ---------------- MFMA split-bf16 GEMM: H = A[N x K] @ W[K x 256] ----------------
// 128x128 block tile, 256 threads (2x2 waves), each wave 4x4 frags of 16x16x32.
// LDS tiles XOR-swizzled: row r, stored chunk c (16B) holds global k-chunk c^(r&3).
__global__ __launch_bounds__(256) void k_gemm(const ushort_t* __restrict__ Ah,
                                              const ushort_t* __restrict__ Al,
                                              const ushort_t* __restrict__ Wh,
                                              const ushort_t* __restrict__ Wl,
                                              float* __restrict__ H, int K) {
    __shared__ ushort_t sm[4 * 128 * 32]; // 32 KB: Ah|Al|Wh|Wl tiles, 128 rows x 32 k each
    ushort_t* tAh = sm;
    ushort_t* tAl = sm + 4096;
    ushort_t* tWh = sm + 8192;
    ushort_t* tWl = sm + 12288;

    int tid = threadIdx.x;
    int lane = tid & 63;
    int w = tid >> 6;
    int wrow = w & 1, wcol = w >> 1;
    int row0 = blockIdx.x * 128;
    int col0 = blockIdx.y * 128;

    // staging role: wave w stages tile w
    const ushort_t* gsrc = (w == 0) ? Ah : (w == 1) ? Al : (w == 2) ? Wh : Wl;
    int rbase = (w < 2) ? row0 : col0;
    int rlimit = (w < 2) ? N_NODES : (col0 + 128);
    ushort_t* ldst = sm + w * 4096;
    int srow = lane >> 2;        // row within 16-row group
    int sch = lane & 3;          // stored chunk

    f32x4 acc[4][4] = {};
    int m = lane & 15, q = lane >> 4;

    for (int k0 = 0; k0 < K; k0 += 32) {
        #pragma unroll
        for (int i = 0; i < 8; ++i) {
            int r = i * 16 + srow;
            int grow = rbase + r;
            int gch = sch ^ (r & 3);
            if (grow < rlimit)
                gl_lds16(gsrc + (size_t)grow * K + k0 + gch * 8, ldst + i * 512);
        }
        __syncthreads();

        bf16x8 ahf[4], alf[4], whf[4], wlf[4];
        #pragma unroll
        for (int r = 0; r < 4; ++r) {
            int rr = wrow * 64 + r * 16 + m;
            int off = rr * 32 + ((q ^ (rr & 3)) << 3);
            ahf[r] = *(const bf16x8*)(tAh + off);
            alf[r] = *(const bf16x8*)(tAl + off);
        }
        #pragma unroll
        for (int c = 0; c < 4; ++c) {
            int nn = wcol * 64 + c * 16 + m;
            int off = nn * 32 + ((q ^ (nn & 3)) << 3);
            whf[c] = *(const bf16x8*)(tWh + off);
            wlf[c] = *(const bf16x8*)(tWl + off);
        }
        #pragma unroll
        for (int r = 0; r < 4; ++r)
            #pragma unroll
            for (int c = 0; c < 4; ++c) {
                acc[r][c] = __builtin_amdgcn_mfma_f32_16x16x32_bf16(ahf[r], whf[c], acc[r][c], 0, 0, 0);
                acc[r][c] = __builtin_amdgcn_mfma_f32_16x16x32_bf16(ahf[r], wlf[c], acc[r][c], 0, 0, 0);
                acc[r][c] = __builtin_amdgcn_mfma_f32_16x16x32_bf16(alf[r], whf[c], acc[r][c], 0, 0, 0);
                acc[r][c] = __builtin_amdgcn_mfma_f32_16x16x32_bf16(alf[r], wlf[c], acc[r][c], 0, 0, 0);
            }
        __syncthreads();
    }

    #pragma unroll
    for (int r = 0; r < 4; ++r) {
        int mrow = row0 + wrow * 64 + r * 16 + (lane >> 4) * 4;
        #pragma unroll
        for (int c = 0; c < 4; ++c) {
            int n = col0 + wcol * 64 + c * 16 + (lane & 15);
            f32x4 v = acc[r][c];
            #pragma unroll
            for (int g = 0; g < 4; ++g)
                if (mrow + g < N_NODES)
                    H[(size_t)(mrow + g) * HID + n] = v[g];
        }
    }
}

// ---------------- BN prep (bias folded) ----------------
__global__ void k_bnprep(const float* __restrict__ gamma, const float* __restrict__ beta,
                         const float* __restrict__ mean, const float* __restrict__ var,
                         const float* __restrict__ bias,
                         float* __restrict__ scale, float* __restrict__ shift) {
    int l = blockIdx.x;
    int c = threadIdx.x;
    if (c < HID) {
        float s = gamma[l * HID + c] * rsqrtf(var[l * HID + c] + BN_EPS);
        scale[l * HID + c] = s;
        shift[l * HID + c] = beta[l * HID + c] + (bias[l * HID + c] - mean[l * HID + c]) * s;
    }
}

// ---------------- fused gather + self-loop + BN + ReLU (common body) ----------------
__device__ __forceinline__ float4 gather_body(const float* __restrict__ H,
                                              const int* __restrict__ rowstart,
                                              const int* __restrict__ esrc,
                                              const float* __restrict__ ew,
                                              const float* __restrict__ selfn,
                                              const float* __restrict__ bnscale,
                                              const float* __restrict__ bnshift,
                                              int node, int c) {
    int beg = rowstart[node];
    int end = rowstart[node + 1];
    float4 h = *(const float4*)(H + (size_t)node * HID + c);
    float sn = selfn[node];
    float4 acc;
    acc.x = h.x * sn; acc.y = h.y * sn; acc.z = h.z * sn; acc.w = h.w * sn;
    int j = beg;
    for (; j + 1 < end; j += 2) {
        int s0 = esrc[j];
        int s1 = esrc[j + 1];
        float w0 = ew[j];
        float w1 = ew[j + 1];
        float4 v0 = *(const float4*)(H + (size_t)s0 * HID + c);
        float4 v1 = *(const float4*)(H + (size_t)s1 * HID + c);
        acc.x = fmaf(v0.x, w0, acc.x); acc.x = fmaf(v1.x, w1, acc.x);
        acc.y = fmaf(v0.y, w0, acc.y); acc.y = fmaf(v1.y, w1, acc.y);
        acc.z = fmaf(v0.z, w0, acc.z); acc.z = fmaf(v1.z, w1, acc.z);
        acc.w = fmaf(v0.w, w0, acc.w); acc.w = fmaf(v1.w, w1, acc.w);
    }
    if (j < end) {
        int s0 = esrc[j];
        float w0 = ew[j];
        float4 v0 = *(const float4*)(H + (size_t)s0 * HID + c);
        acc.x = fmaf(v0.x, w0, acc.x);
        acc.y = fmaf(v0.y, w0, acc.y);
        acc.z = fmaf(v0.z, w0, acc.z);
        acc.w = fmaf(v0.w, w0, acc.w);
    }
    float4 sc = *(const float4*)(bnscale + c);
    float4 sh = *(const float4*)(bnshift + c);
    float4 o;
    o.x = fmaxf(fmaf(acc.x, sc.x, sh.x), 0.f);
    o.y = fmaxf(fmaf(acc.y, sc.y, sh.y), 0.f);
    o.z = fmaxf(fmaf(acc.z, sc.z, sh.z), 0.f);
    o.w = fmaxf(fmaf(acc.w, sc.w, sh.w), 0.f);
    return o;
}

// variant A: write bf16 hi/lo (feeds next layer's MFMA GEMM)
__global__ __launch_bounds__(256) void k_gather_bf(const float* __restrict__ H,
                                                   const int* __restrict__ rowstart,
                                                   const int* __restrict__ esrc,
                                                   const float* __restrict__ ew,
                                                   const float* __restrict__ selfn,
                                                   const float* __restrict__ bnscale,
                                                   const float* __restrict__ bnshift,
                                                   ushort_t* __restrict__ Xh,
                                                   ushort_t* __restrict__ Xl, int N) {
    int node = blockIdx.x * 4 + (threadIdx.x >> 6);
    if (node >= N) return;
    int c = (threadIdx.x & 63) * 4;
    float4 o = gather_body(H, rowstart, esrc, ew, selfn, bnscale, bnshift, node, c);
    ushort4 h, l;
    h.x = f2bf_rn(o.x); l.x = f2bf_rn(o.x - bf2f(h.x));
    h.y = f2bf_rn(o.y); l.y = f2bf_rn(o.y - bf2f(h.y));
    h.z = f2bf_rn(o.z); l.z = f2bf_rn(o.z - bf2f(h.z));
    h.w = f2bf_rn(o.w); l.w = f2bf_rn(o.w - bf2f(h.w));
    *(ushort4*)(Xh + (size_t)node * HID + c) = h;
    *(ushort4*)(Xl + (size_t)node * HID + c) = l;
}

// variant B: write fp32 (last layer, feeds pool)
__global__ __launch_bounds__(256) void k_gather_f32(const float* __restrict__ H,
                                                    const int* __restrict__ rowstart,
                                                    const int* __restrict__ esrc,
                                                    const float* __restrict__ ew,
                                                    const float* __restrict__ selfn,
                                                    const float* __restrict__ bnscale,
                                                    const float* __restrict__ bnshift,
                                                    float* __restrict__ X, int N) {
    int node = blockIdx.x * 4 + (threadIdx.x >> 6);
    if (node >= N) return;
    int c = (threadIdx.x & 63) * 4;
    float4 o = gather_body(H, rowstart, esrc, ew, selfn, bnscale, bnshift, node, c);
    *(float4*)(X + (size_t)node * HID + c) = o;
}

// ---------------- segmented mean pool ----------------
#define POOL_SPAN 25
__global__ __launch_bounds__(256) void k_pool(const float* __restrict__ X,
                                              const int* __restrict__ batch,
                                              float* __restrict__ pooled,
                                              int* __restrict__ cnt, int N) {
    int n0 = blockIdx.x * POOL_SPAN;
    int c = threadIdx.x;
    int nend = min(n0 + POOL_SPAN, N);
    float acc = 0.f;
    int curg = batch[n0];
    int segcnt = 0;
    for (int n = n0; n < nend; ++n) {
        int g = batch[n];
        if (g != curg) {
            atomicAdd(&pooled[(size_t)curg * HID + c], acc);
            if (c == 0) atomicAdd(&cnt[curg], segcnt);
            acc = 0.f;
            segcnt = 0;
            curg = g;
        }
        acc += X[(size_t)n * HID + c];
        ++segcnt;
    }
    atomicAdd(&pooled[(size_t)curg * HID + c], acc);
    if (c == 0) atomicAdd(&cnt[curg], segcnt);
}

// ---------------- MLP head ----------------
__global__ __launch_bounds__(128) void k_mlp(const float* __restrict__ pooled,
                                             const int* __restrict__ cnt,
                                             const float* __restrict__ W1,
                                             const float* __restrict__ b1,
                                             const float* __restrict__ W2,
                                             const float* __restrict__ b2,
                                             float* __restrict__ out) {
    __shared__ float prow[HID];
    __shared__ float hred[2];
    int g = blockIdx.x;
    int j = threadIdx.x;
    prow[j] = pooled[(size_t)g * HID + j];
    prow[j + 128] = pooled[(size_t)g * HID + 128 + j];
    __syncthreads();
    float acc = 0.f;
    #pragma unroll 8
    for (int k = 0; k < HID; ++k) acc += prow[k] * W1[k * 128 + j];
    float inv = 1.0f / fmaxf((float)cnt[g], 1.0f);
    float h = fmaxf(acc * inv + b1[j], 0.f);
    float p = h * W2[j];
    #pragma unroll
    for (int off = 32; off > 0; off >>= 1) p += __shfl_down(p, off, 64);
    if ((j & 63) == 0) hred[j >> 6] = p;
    __syncthreads();
    if (j == 0) out[g] = hred[0] + hred[1] + b2[0];
}

extern "C" void kernel_launch(void* const* d_in, const int* in_sizes, int n_in,
                              void* d_out, int out_size, void* d_ws, size_t ws_size,
                              hipStream_t stream) {
    const float* x      = (const float*)d_in[0];
    const int*   ei     = (const int*)d_in[1];
    const int*   batch  = (const int*)d_in[2];
    const float* convW0 = (const float*)d_in[3];
    const float* convWs = (const float*)d_in[4];
    const float* convB  = (const float*)d_in[5];
    const float* gamma  = (const float*)d_in[6];
    const float* beta   = (const float*)d_in[7];
    const float* mean   = (const float*)d_in[8];
    const float* var    = (const float*)d_in[9];
    const float* lin1W  = (const float*)d_in[10];
    const float* lin1b  = (const float*)d_in[11];
    const float* lin2W  = (const float*)d_in[12];
    const float* lin2b  = (const float*)d_in[13];
    float* out = (float*)d_out;

    const int* src = ei;
    const int* dst = ei + N_EDGES;

    const int WTOT = 128 * 256 + 3 * 256 * 256; // 229376

    float* ws = (float*)d_ws;
    float* xbuf = ws;                                    // N*HID fp32 (layer3 out)
    float* hbuf = xbuf + (size_t)N_NODES * HID;          // N*HID fp32
    ushort_t* Ahb = (ushort_t*)(hbuf + (size_t)N_NODES * HID); // N*HID ushort
    ushort_t* Alb = Ahb + (size_t)N_NODES * HID;         // N*HID ushort
    ushort_t* WhT = Alb + (size_t)N_NODES * HID;         // WTOT ushort
    ushort_t* WlT = WhT + WTOT;                          // WTOT ushort
    float* dinv    = (float*)(WlT + WTOT);               // N
    float* selfn   = dinv + N_NODES;                     // N
    float* ew      = selfn + N_NODES;                    // E
    float* pooled  = ew + N_EDGES;                       // G*HID
    float* bnscale = pooled + (size_t)N_GRAPHS * HID;    // 4*HID
    float* bnshift = bnscale + N_LAYERS * HID;           // 4*HID
    int*   cnt     = (int*)(bnshift + N_LAYERS * HID);   // G
    int*   degi    = cnt + N_GRAPHS;                     // N
    int*   rowstart= degi + N_NODES;                     // N+1
    int*   cursor  = rowstart + (N_NODES + 1);           // N
    int*   esrc    = cursor + N_NODES;                   // E

    hipMemsetAsync(degi, 0, (size_t)N_NODES * 4, stream);
    hipMemsetAsync(pooled, 0, (size_t)N_GRAPHS * HID * 4, stream);
    hipMemsetAsync(cnt, 0, (size_t)N_GRAPHS * 4, stream);

    // CSR build + norms
    k_deg<<<(N_EDGES + 255) / 256, 256, 0, stream>>>(dst, degi, N_EDGES);
    k_nodenorm<<<(N_NODES + 255) / 256, 256, 0, stream>>>(degi, dinv, selfn, N_NODES);
    k_scan<<<1, 1024, 0, stream>>>(degi, rowstart, cursor, N_NODES);
    k_fill<<<(N_EDGES + 255) / 256, 256, 0, stream>>>(src, dst, dinv, cursor, esrc, ew, N_EDGES);

    // prep: BN affine, weight split (transposed), x split
    k_bnprep<<<N_LAYERS, 256, 0, stream>>>(gamma, beta, mean, var, convB, bnscale, bnshift);
    k_splitw<<<(WTOT + 255) / 256, 256, 0, stream>>>(convW0, convWs, WhT, WlT);
    k_splitx<<<(N_NODES * IN_DIM / 4 + 255) / 256, 256, 0, stream>>>(x, Ahb, Alb, N_NODES * IN_DIM / 4);

    dim3 gg((N_NODES + 127) / 128, HID / 128);
    for (int l = 0; l < N_LAYERS; ++l) {
        int K = (l == 0) ? IN_DIM : HID;
        size_t woff = (l == 0) ? 0 : (size_t)(32768 + (l - 1) * 65536);
        k_gemm<<<gg, 256, 0, stream>>>(Ahb, Alb, WhT + woff, WlT + woff, hbuf, K);
        if (l < N_LAYERS - 1)
            k_gather_bf<<<(N_NODES + 3) / 4, 256, 0, stream>>>(hbuf, rowstart, esrc, ew, selfn,
                                                               bnscale + l * HID, bnshift + l * HID,
                                                               Ahb, Alb, N_NODES);
        else
            k_gather_f32<<<(N_NODES + 3) / 4, 256, 0, stream>>>(hbuf, rowstart, esrc, ew, selfn,
                                                                bnscale + l * HID, bnshift + l * HID,
                                                                xbuf, N_NODES);
    }

    k_pool<<<(N_NODES + POOL_SPAN - 1) / POOL_SPAN, 256, 0, stream>>>(xbuf, batch, pooled, cnt, N_NODES);
    k_mlp<<<N_GRAPHS, 128, 0, stream>>>(pooled, cnt, lin1W, lin1b, lin2W, lin2b, out);
}